// Round 1
// baseline (844.985 us; speedup 1.0000x reference)
//
#include <hip/hip_runtime.h>
#include <hip/hip_bf16.h>
#include <cmath>

#define ENCD 128
#define DECD 128
#define CHUNK 8

// ---------------- init: zero the histogram counters ----------------
__global__ void init_counts(int* __restrict__ counts, int B) {
    int i = blockIdx.x * blockDim.x + threadIdx.x;
    if (i < B) counts[i] = 0;
}

// ---------------- qW = query[B,128] @ W[128,128] ----------------
// block = 256 threads, 8 query rows per block; thread (rh,c) computes 4 rows x 1 col.
__global__ void qw_gemm(const float* __restrict__ query, const float* __restrict__ W,
                        float* __restrict__ qW) {
    __shared__ float qs[8][DECD];
    const int t = threadIdx.x;
    const int row0 = blockIdx.x * 8;
    for (int i = t; i < 8 * DECD; i += 256)
        qs[i >> 7][i & 127] = query[(size_t)row0 * DECD + i];
    __syncthreads();
    const int c = t & 127;
    const int rh = t >> 7;  // 0..1
    float a0 = 0.f, a1 = 0.f, a2 = 0.f, a3 = 0.f;
    for (int k = 0; k < DECD; ++k) {
        const float w = W[k * ENCD + c];        // coalesced; W L1/L2-resident
        a0 += qs[rh * 4 + 0][k] * w;            // LDS broadcast (free)
        a1 += qs[rh * 4 + 1][k] * w;
        a2 += qs[rh * 4 + 2][k] * w;
        a3 += qs[rh * 4 + 3][k] * w;
    }
    qW[(size_t)(row0 + rh * 4 + 0) * ENCD + c] = a0;
    qW[(size_t)(row0 + rh * 4 + 1) * ENCD + c] = a1;
    qW[(size_t)(row0 + rh * 4 + 2) * ENCD + c] = a2;
    qW[(size_t)(row0 + rh * 4 + 3) * ENCD + c] = a3;
}

// ---------------- CSR build ----------------
__global__ void hist_kernel(const int* __restrict__ index, int* __restrict__ counts, int N) {
    int n = blockIdx.x * blockDim.x + threadIdx.x;
    if (n < N) atomicAdd(&counts[index[n]], 1);
}

// single block, 1024 threads, scans up to 8192 counters (B=8192 here)
__global__ void scan_kernel(const int* __restrict__ counts, int* __restrict__ offsets,
                            int* __restrict__ cursor, int B) {
    __shared__ int tot[1024];
    const int t = threadIdx.x;
    int local[8];
    int s = 0;
#pragma unroll
    for (int i = 0; i < 8; ++i) {
        const int ci = t * 8 + i;
        local[i] = (ci < B) ? counts[ci] : 0;
        s += local[i];
    }
    tot[t] = s;
    __syncthreads();
    for (int off = 1; off < 1024; off <<= 1) {   // Hillis-Steele inclusive scan
        int v = (t >= off) ? tot[t - off] : 0;
        __syncthreads();
        tot[t] += v;
        __syncthreads();
    }
    int excl = tot[t] - s;
#pragma unroll
    for (int i = 0; i < 8; ++i) {
        const int ci = t * 8 + i;
        if (ci < B) { offsets[ci] = excl; cursor[ci] = excl; }
        excl += local[i];
    }
    if (t == 1023) offsets[B] = tot[1023];
}

__global__ void scatter_kernel(const int* __restrict__ index, int* __restrict__ cursor,
                               int* __restrict__ nodeids, int N) {
    int n = blockIdx.x * blockDim.x + threadIdx.x;
    if (n < N) {
        const int p = atomicAdd(&cursor[index[n]], 1);
        nodeids[p] = n;
    }
}

// ---------------- main: per-segment online-softmax pooling ----------------
// one block (128 threads = 2 waves) per segment; values streamed from HBM exactly once.
__global__ __launch_bounds__(128) void seg_attn(
    const float* __restrict__ values, const float* __restrict__ qW,
    const int* __restrict__ offsets, const int* __restrict__ nodeids,
    float* __restrict__ out) {
    const int b = blockIdx.x;
    const int t = threadIdx.x;
    const int beg = offsets[b];
    const int cnt = offsets[b + 1] - beg;

    __shared__ float qsh[ENCD];
    __shared__ float vrow[CHUNK][ENCD + 4];  // +4 pad: dot-phase reads 4-way instead of 16-way
    __shared__ float s_sh[CHUNK];
    __shared__ int   nid_sh[CHUNK];

    qsh[t] = qW[(size_t)b * ENCD + t];
    __syncthreads();

    const int g  = t & 15;   // lane within 16-lane dot group
    const int jn = t >> 4;   // which of the 8 chunk nodes this group handles
    float qreg[8];
#pragma unroll
    for (int i = 0; i < 8; ++i) qreg[i] = qsh[g * 8 + i];

    float m = -INFINITY, l = 0.f, acc = 0.f;
    const float inv_sqrt_d = 0.08838834764831845f;  // 1/sqrt(128)

    for (int base = 0; base < cnt; base += CHUNK) {
        const int nim = min(CHUNK, cnt - base);
        // clamp padded slots to a valid node so staged data is finite (p=0 kills it)
        if (t < CHUNK) nid_sh[t] = nodeids[beg + ((t < nim) ? (base + t) : base)];
        __syncthreads();  // S1: nid visible; prev-iter vrow reads complete

        // stage 8 rows: 32 lanes x float4 per row, 2 rows per wave pass
        {
            const int r0 = t >> 5;          // 0..3
            const int c4 = (t & 31) * 4;    // float col
#pragma unroll
            for (int it = 0; it < 2; ++it) {
                const int r = r0 + it * 4;
                const float4 v = *(const float4*)(values + (size_t)nid_sh[r] * ENCD + c4);
                *(float4*)&vrow[r][c4] = v;
            }
        }
        __syncthreads();  // S2: vrow staged

        // dots: 16 lanes per node, 8 cols each, shuffle-reduce within the 16-lane group
        float pd = 0.f;
#pragma unroll
        for (int i = 0; i < 8; ++i) pd += qreg[i] * vrow[jn][g * 8 + i];
        pd += __shfl_xor(pd, 1);
        pd += __shfl_xor(pd, 2);
        pd += __shfl_xor(pd, 4);
        pd += __shfl_xor(pd, 8);
        if (g == 0) s_sh[jn] = (jn < nim) ? pd * inv_sqrt_d : -INFINITY;
        __syncthreads();  // S3: s_sh visible

        // online-softmax update (every thread keeps consistent m,l; thread t owns col t)
        float sv[CHUNK];
        float m_ch = -INFINITY;
#pragma unroll
        for (int j = 0; j < CHUNK; ++j) { sv[j] = s_sh[j]; m_ch = fmaxf(m_ch, sv[j]); }
        const float m_new = fmaxf(m, m_ch);
        const float scale = __expf(m - m_new);   // first iter: exp(-inf - finite) = 0
        float psum = 0.f, accadd = 0.f;
#pragma unroll
        for (int j = 0; j < CHUNK; ++j) {
            const float p = __expf(sv[j] - m_new);       // padded j: exp(-inf)=0
            psum += p;
            accadd += p * vrow[j][t];                    // 2-way LDS read = free
        }
        l = l * scale + psum;
        acc = acc * scale + accadd;
        m = m_new;
        // no trailing sync needed: S1 of next iter orders vrow reads vs restaging
    }

    out[(size_t)b * ENCD + t] = (l > 0.f) ? (acc / l) : 0.f;
}

extern "C" void kernel_launch(void* const* d_in, const int* in_sizes, int n_in,
                              void* d_out, int out_size, void* d_ws, size_t ws_size,
                              hipStream_t stream) {
    const float* query  = (const float*)d_in[0];   // [B,128]
    const float* values = (const float*)d_in[1];   // [N,128]
    const int*   index  = (const int*)d_in[2];     // [N]
    const float* W      = (const float*)d_in[3];   // [128,128]
    float* out = (float*)d_out;                    // [B,128]

    const int B = in_sizes[0] / DECD;   // 8192
    const int N = in_sizes[2];          // 1,000,000

    // workspace carve (~8.3 MB)
    float* qW      = (float*)d_ws;                    // B*128 floats
    int*   nodeids = (int*)(qW + (size_t)B * ENCD);   // N ints
    int*   counts  = nodeids + N;                     // B
    int*   offsets = counts + B;                      // B+1
    int*   cursor  = offsets + B + 1;                 // B

    init_counts<<<(B + 255) / 256, 256, 0, stream>>>(counts, B);
    qw_gemm<<<B / 8, 256, 0, stream>>>(query, W, qW);
    hist_kernel<<<(N + 255) / 256, 256, 0, stream>>>(index, counts, N);
    scan_kernel<<<1, 1024, 0, stream>>>(counts, offsets, cursor, B);
    scatter_kernel<<<(N + 255) / 256, 256, 0, stream>>>(index, cursor, nodeids, N);
    seg_attn<<<B, 128, 0, stream>>>(values, qW, offsets, nodeids, out);
}

// Round 2
// 837.693 us; speedup vs baseline: 1.0087x; 1.0087x over previous
//
#include <hip/hip_runtime.h>
#include <hip/hip_bf16.h>
#include <cmath>

#define ENCD 128
#define DECD 128
#define CHUNK 32

// ---------------- init: zero the histogram counters ----------------
__global__ void init_counts(int* __restrict__ counts, int B) {
    int i = blockIdx.x * blockDim.x + threadIdx.x;
    if (i < B) counts[i] = 0;
}

// ---------------- qW = query[B,128] @ W[128,128] ----------------
// block = 256 threads, 8 query rows per block; thread (rh,c) computes 4 rows x 1 col.
__global__ void qw_gemm(const float* __restrict__ query, const float* __restrict__ W,
                        float* __restrict__ qW) {
    __shared__ float qs[8][DECD];
    const int t = threadIdx.x;
    const int row0 = blockIdx.x * 8;
    for (int i = t; i < 8 * DECD; i += 256)
        qs[i >> 7][i & 127] = query[(size_t)row0 * DECD + i];
    __syncthreads();
    const int c = t & 127;
    const int rh = t >> 7;  // 0..1
    float a0 = 0.f, a1 = 0.f, a2 = 0.f, a3 = 0.f;
    for (int k = 0; k < DECD; ++k) {
        const float w = W[k * ENCD + c];        // coalesced; W L1/L2-resident
        a0 += qs[rh * 4 + 0][k] * w;            // LDS broadcast (free)
        a1 += qs[rh * 4 + 1][k] * w;
        a2 += qs[rh * 4 + 2][k] * w;
        a3 += qs[rh * 4 + 3][k] * w;
    }
    qW[(size_t)(row0 + rh * 4 + 0) * ENCD + c] = a0;
    qW[(size_t)(row0 + rh * 4 + 1) * ENCD + c] = a1;
    qW[(size_t)(row0 + rh * 4 + 2) * ENCD + c] = a2;
    qW[(size_t)(row0 + rh * 4 + 3) * ENCD + c] = a3;
}

// ---------------- CSR build ----------------
__global__ void hist_kernel(const int* __restrict__ index, int* __restrict__ counts, int N) {
    int n4 = (blockIdx.x * blockDim.x + threadIdx.x) * 4;
    if (n4 + 3 < N) {
        const int4 v = *(const int4*)(index + n4);
        atomicAdd(&counts[v.x], 1);
        atomicAdd(&counts[v.y], 1);
        atomicAdd(&counts[v.z], 1);
        atomicAdd(&counts[v.w], 1);
    } else {
        for (int n = n4; n < N; ++n) atomicAdd(&counts[index[n]], 1);
    }
}

// single block, 1024 threads, scans up to 8192 counters (B=8192 here)
__global__ void scan_kernel(const int* __restrict__ counts, int* __restrict__ offsets,
                            int* __restrict__ cursor, int B) {
    __shared__ int tot[1024];
    const int t = threadIdx.x;
    int local[8];
    int s = 0;
#pragma unroll
    for (int i = 0; i < 8; ++i) {
        const int ci = t * 8 + i;
        local[i] = (ci < B) ? counts[ci] : 0;
        s += local[i];
    }
    tot[t] = s;
    __syncthreads();
    for (int off = 1; off < 1024; off <<= 1) {   // Hillis-Steele inclusive scan
        int v = (t >= off) ? tot[t - off] : 0;
        __syncthreads();
        tot[t] += v;
        __syncthreads();
    }
    int excl = tot[t] - s;
#pragma unroll
    for (int i = 0; i < 8; ++i) {
        const int ci = t * 8 + i;
        if (ci < B) { offsets[ci] = excl; cursor[ci] = excl; }
        excl += local[i];
    }
    if (t == 1023) offsets[B] = tot[1023];
}

__global__ void scatter_kernel(const int* __restrict__ index, int* __restrict__ cursor,
                               int* __restrict__ nodeids, int N) {
    int n = blockIdx.x * blockDim.x + threadIdx.x;
    if (n < N) {
        const int p = atomicAdd(&cursor[index[n]], 1);
        nodeids[p] = n;
    }
}

// ---------------- main: per-segment online-softmax pooling ----------------
// one block (256 threads = 4 waves) per segment; values streamed from HBM exactly once.
// CHUNK=32 rows staged per barrier interval -> 4 independent float4 loads in
// flight per thread, 4x fewer barriers per node than CHUNK=8.
__global__ __launch_bounds__(256) void seg_attn(
    const float* __restrict__ values, const float* __restrict__ qW,
    const int* __restrict__ offsets, const int* __restrict__ nodeids,
    float* __restrict__ out) {
    const int b = blockIdx.x;
    const int t = threadIdx.x;
    const int beg = offsets[b];
    const int cnt = offsets[b + 1] - beg;

    __shared__ float qsh[ENCD];
    __shared__ float vrow[CHUNK][ENCD + 4];  // +4 pad breaks power-of-2 bank stride
    __shared__ float s_sh[CHUNK];
    __shared__ int   nid_sh[CHUNK];
    __shared__ float mrg_a[ENCD];
    __shared__ float mrg_l[ENCD];

    if (t < ENCD) qsh[t] = qW[(size_t)b * ENCD + t];
    __syncthreads();

    const int g  = t & 15;   // lane within 16-lane dot group
    const int jn = t >> 4;   // node-group 0..15
    float qreg[8];
#pragma unroll
    for (int i = 0; i < 8; ++i) qreg[i] = qsh[g * 8 + i];

    const int col  = t & 127;   // accumulator column this thread owns
    const int half = t >> 7;    // 0: rows 0..15, 1: rows 16..31

    float m = -INFINITY, l = 0.f, acc = 0.f;
    const float inv_sqrt_d = 0.08838834764831845f;  // 1/sqrt(128)

    for (int base = 0; base < cnt; base += CHUNK) {
        const int nim = min(CHUNK, cnt - base);
        // clamp padded slots to a valid node so staged data is finite (p=0 kills it)
        if (t < CHUNK) nid_sh[t] = nodeids[beg + ((t < nim) ? (base + t) : base)];
        __syncthreads();  // S1: nid visible; prev-iter vrow reads complete

        // stage 32 rows: 32 lanes x float4 per row, 8 rows per 256-thread pass, 4 passes
        {
            const int r0 = t >> 5;          // 0..7
            const int c4 = (t & 31) * 4;    // float col
#pragma unroll
            for (int it = 0; it < 4; ++it) {
                const int r = r0 + it * 8;
                const float4 v = *(const float4*)(values + (size_t)nid_sh[r] * ENCD + c4);
                *(float4*)&vrow[r][c4] = v;
            }
        }
        __syncthreads();  // S2: vrow staged

        // dots: 16 lanes per node, 8 cols each, 2 nodes per thread
#pragma unroll
        for (int p = 0; p < 2; ++p) {
            const int j = jn + p * 16;
            float pd = 0.f;
#pragma unroll
            for (int i = 0; i < 8; ++i) pd += qreg[i] * vrow[j][g * 8 + i];
            pd += __shfl_xor(pd, 1);
            pd += __shfl_xor(pd, 2);
            pd += __shfl_xor(pd, 4);
            pd += __shfl_xor(pd, 8);
            if (g == 0) s_sh[j] = (j < nim) ? pd * inv_sqrt_d : -INFINITY;
        }
        __syncthreads();  // S3: s_sh visible

        // online-softmax update. All threads compute the identical m-sequence
        // (max over all 32 scores); each half-block accumulates 16 of the 32 rows
        // for its column, merged once after the loop (valid: same m per step).
        float m_ch = -INFINITY;
#pragma unroll
        for (int j = 0; j < CHUNK; ++j) m_ch = fmaxf(m_ch, s_sh[j]);  // LDS broadcast
        const float m_new = fmaxf(m, m_ch);
        const float scale = __expf(m - m_new);   // first iter: exp(-inf) = 0
        float psum = 0.f, accadd = 0.f;
#pragma unroll
        for (int jj = 0; jj < 16; ++jj) {
            const int j = half * 16 + jj;
            const float p = __expf(s_sh[j] - m_new);   // padded j: exp(-inf)=0
            psum += p;
            accadd += p * vrow[j][col];                // stride-1 across lanes, conflict-free
        }
        l = l * scale + psum;
        acc = acc * scale + accadd;
        m = m_new;
        // no trailing sync: S1 of next iter orders vrow reads vs restaging
    }

    // merge the two half-block partial accumulators
    if (half == 1) { mrg_a[col] = acc; mrg_l[col] = l; }
    __syncthreads();
    if (half == 0) {
        const float at = acc + mrg_a[col];
        const float lt = l + mrg_l[col];
        out[(size_t)b * ENCD + col] = (lt > 0.f) ? (at / lt) : 0.f;
    }
}

extern "C" void kernel_launch(void* const* d_in, const int* in_sizes, int n_in,
                              void* d_out, int out_size, void* d_ws, size_t ws_size,
                              hipStream_t stream) {
    const float* query  = (const float*)d_in[0];   // [B,128]
    const float* values = (const float*)d_in[1];   // [N,128]
    const int*   index  = (const int*)d_in[2];     // [N]
    const float* W      = (const float*)d_in[3];   // [128,128]
    float* out = (float*)d_out;                    // [B,128]

    const int B = in_sizes[0] / DECD;   // 8192
    const int N = in_sizes[2];          // 1,000,000

    // workspace carve (~8.3 MB)
    float* qW      = (float*)d_ws;                    // B*128 floats
    int*   nodeids = (int*)(qW + (size_t)B * ENCD);   // N ints
    int*   counts  = nodeids + N;                     // B
    int*   offsets = counts + B;                      // B+1
    int*   cursor  = offsets + B + 1;                 // B

    init_counts<<<(B + 255) / 256, 256, 0, stream>>>(counts, B);
    qw_gemm<<<B / 8, 256, 0, stream>>>(query, W, qW);
    hist_kernel<<<(N / 4 + 255) / 256, 256, 0, stream>>>(index, counts, N);
    scan_kernel<<<1, 1024, 0, stream>>>(counts, offsets, cursor, B);
    scatter_kernel<<<(N + 255) / 256, 256, 0, stream>>>(index, cursor, nodeids, N);
    seg_attn<<<B, 256, 0, stream>>>(values, qW, offsets, nodeids, out);
}